// Round 8
// baseline (691.546 us; speedup 1.0000x reference)
//
#include <hip/hip_runtime.h>
#include <hip/hip_fp16.h>

// Affinity propagation: 24 Jacobi iterations of an 8-neighbor weighted stencil.
// OFFSETS (dy,dx): (-1,-1),(-1,0),(-1,1),(0,-1),(0,1),(1,-1),(1,0),(1,1)
// R8 = R7 (register-resident state, DPP horizontal exchange, LDS vertical
// exchange, FUSE=8 x 3 launches) + register diet: bias kept packed fp16
// (8 VGPR), __launch_bounds__(256,4) to force VGPR<=128 -> 4 blocks/CU
// (R7 was ~3/CU: 768 co-resident of 1120 -> 46%-occupancy tail phase).

#define EPSV 1e-6f
#define FUSE   8
#define CORE   48                 // output core per 64x64 tile
#define TXN    14                 // ceil(640/48)
#define TYN    10                 // 480/48
#define NBLK   (8 * TXN * TYN)    // 1120

typedef __attribute__((ext_vector_type(8))) _Float16 half8;
typedef __attribute__((ext_vector_type(4))) _Float16 half4;

__device__ __forceinline__ float dpp_from_left(float v) {
    // lane i gets lane i-1's v (within 16-lane DPP row); qx==0 -> 0.
    int r = __builtin_amdgcn_update_dpp(0, __float_as_int(v), 0x111, 0xF, 0xF, true);
    return __int_as_float(r);
}
__device__ __forceinline__ float dpp_from_right(float v) {
    // lane i gets lane i+1's v; qx==15 -> 0.
    int r = __builtin_amdgcn_update_dpp(0, __float_as_int(v), 0x101, 0xF, 0xF, true);
    return __int_as_float(r);
}

// ---------------------------------------------------------------------------
// Kernel 1: normalize guidance -> fp16 weights (AoS), fp16 bias, fp16 state.
// ---------------------------------------------------------------------------
__global__ __launch_bounds__(256) void precompute_kernel(
    const float* __restrict__ guidance, const float* __restrict__ raw,
    half8* __restrict__ wgt, _Float16* __restrict__ bias,
    _Float16* __restrict__ state, int B, int H, int W)
{
    int idx = blockIdx.x * blockDim.x + threadIdx.x;
    int total = B * H * W;
    if (idx >= total) return;
    int x = idx % W;
    int y = (idx / W) % H;
    int b = idx / (W * H);

    const int dy[8] = {-1,-1,-1, 0, 0, 1, 1, 1};
    const int dx[8] = {-1, 0, 1,-1, 1,-1, 0, 1};

    float g[8];
    float s = 0.f;
#pragma unroll
    for (int c = 0; c < 8; ++c) {
        int yy = y + dy[c], xx = x + dx[c];
        float v = 0.f;
        if (yy >= 0 && yy < H && xx >= 0 && xx < W)
            v = guidance[(((size_t)b * 8 + c) * H + yy) * W + xx];
        g[c] = v;
        s += fabsf(v);
    }
    float inv = 1.f / fmaxf(s, EPSV);
    float wsum = 0.f;
#pragma unroll
    for (int c = 0; c < 8; ++c) { g[c] *= inv; wsum += g[c]; }

    half8 hw;
#pragma unroll
    for (int c = 0; c < 8; ++c) hw[c] = (_Float16)g[c];
    wgt[idx] = hw;

    float r = raw[idx];
    bias[idx]  = (_Float16)((1.f - wsum) * r);
    state[idx] = (_Float16)r;
}

// ---------------------------------------------------------------------------
// Kernel 2: FUSE Jacobi iterations with state in registers.
// Tile = 64x64 owned px; outside-tile treated as 0 each iteration (recompute
// ring): after k iters px at distance >= k from tile edge are exact, so the
// 48x48 core (distance 8) is exact at k=FUSE=8. Out-of-image px have
// w=0,b=0,s=0 -> stay 0, matching zero-pad semantics. Cores tile the image
// disjointly, so the last launch writes every output px exactly once.
// ---------------------------------------------------------------------------
template<bool LAST>
__global__ __launch_bounds__(256, 4) void prop_fused_kernel(
    const _Float16* __restrict__ src, const half8* __restrict__ wgt,
    const _Float16* __restrict__ bias, _Float16* __restrict__ dst,
    float* __restrict__ dst32)
{
    const int H = 480, W = 640;
    // bufTop[p][s][x]: strip s's row0 (read as "below-row" by strip s-1 at
    // index s; slot 16 stays 0). bufBot[p][s+1][x]: strip s's row3 (read as
    // "above-row" by strip s+1 at index s+1; slot 0 stays 0).
    __shared__ __align__(16) float bufTop[2][17][64];
    __shared__ __align__(16) float bufBot[2][17][64];

    int tid = threadIdx.x;
    int qx = tid & 15;          // x-quad within tile (DPP row position)
    int sy = tid >> 4;          // 4-row strip within tile

    int t = blockIdx.x;
    int tx = t % TXN;
    int tmp = t / TXN;
    int ty = tmp % TYN;
    int b  = tmp / TYN;
    int x0 = tx * CORE - FUSE;
    int y0 = ty * CORE - FUSE;
    size_t plane = (size_t)b * H * W;

    int gx0 = x0 + qx * 4;                       // quad is fully in or out
    bool xok = (gx0 >= 0) & (gx0 + 3 < W);
    int gyb = y0 + sy * 4;

    if (tid < 64) {
        bufBot[0][0][tid]  = 0.f; bufBot[1][0][tid]  = 0.f;
        bufTop[0][16][tid] = 0.f; bufTop[1][16][tid] = 0.f;
    }

    // Per-px weights (half8 = 4 VGPR), bias packed fp16, state f32.
    half8 pw[4][4];
    half4 pbq[4];
    float s[4][4];
#pragma unroll
    for (int r = 0; r < 4; ++r) {
        int gy = gyb + r;
        bool ok = xok && gy >= 0 && gy < H;
        if (ok) {
            size_t gb = plane + (size_t)gy * W + gx0;
            const half8* wp = wgt + gb;
            pw[r][0] = wp[0]; pw[r][1] = wp[1]; pw[r][2] = wp[2]; pw[r][3] = wp[3];
            pbq[r] = *(const half4*)(bias + gb);
            half4 sq = *(const half4*)(src + gb);
#pragma unroll
            for (int c = 0; c < 4; ++c) s[r][c] = (float)sq[c];
        } else {
            half8 hz;
#pragma unroll
            for (int c = 0; c < 8; ++c) hz[c] = (_Float16)0.f;
            half4 z4;
#pragma unroll
            for (int c = 0; c < 4; ++c) z4[c] = (_Float16)0.f;
            pbq[r] = z4;
#pragma unroll
            for (int c = 0; c < 4; ++c) { pw[r][c] = hz; s[r][c] = 0.f; }
        }
    }

#pragma unroll 2
    for (int it = 0; it < FUSE; ++it) {
        const int p = it & 1;
        // Exchange strip-boundary rows (old values).
        *(float4*)&bufTop[p][sy][qx * 4]     = make_float4(s[0][0], s[0][1], s[0][2], s[0][3]);
        *(float4*)&bufBot[p][sy + 1][qx * 4] = make_float4(s[3][0], s[3][1], s[3][2], s[3][3]);
        __syncthreads();
        float4 Av = *(const float4*)&bufBot[p][sy][qx * 4];      // row above strip
        float4 Bv = *(const float4*)&bufTop[p][sy + 1][qx * 4];  // row below strip

        // Rolling in-place update (wave-uniform, so DPP of carry regs is safe).
        float u0 = Av.x, u1 = Av.y, u2 = Av.z, u3 = Av.w;
        float ul = dpp_from_left(u3);
        float ur = dpp_from_right(u0);
        float cl = dpp_from_left(s[0][3]);
        float cr = dpp_from_right(s[0][0]);
#pragma unroll
        for (int r = 0; r < 4; ++r) {
            float D0, D1, D2, D3;
            if (r < 3) { D0 = s[r+1][0]; D1 = s[r+1][1]; D2 = s[r+1][2]; D3 = s[r+1][3]; }
            else       { D0 = Bv.x;      D1 = Bv.y;      D2 = Bv.z;      D3 = Bv.w; }
            float dl = dpp_from_left(D3);
            float dr = dpp_from_right(D0);
            float C0 = s[r][0], C1 = s[r][1], C2 = s[r][2], C3 = s[r][3];
            half8 w0 = pw[r][0], w1 = pw[r][1], w2 = pw[r][2], w3 = pw[r][3];
            float n0 = (float)pbq[r][0]
                + (float)w0[0] * ul + (float)w0[1] * u0 + (float)w0[2] * u1
                + (float)w0[3] * cl + (float)w0[4] * C1
                + (float)w0[5] * dl + (float)w0[6] * D0 + (float)w0[7] * D1;
            float n1 = (float)pbq[r][1]
                + (float)w1[0] * u0 + (float)w1[1] * u1 + (float)w1[2] * u2
                + (float)w1[3] * C0 + (float)w1[4] * C2
                + (float)w1[5] * D0 + (float)w1[6] * D1 + (float)w1[7] * D2;
            float n2 = (float)pbq[r][2]
                + (float)w2[0] * u1 + (float)w2[1] * u2 + (float)w2[2] * u3
                + (float)w2[3] * C1 + (float)w2[4] * C3
                + (float)w2[5] * D1 + (float)w2[6] * D2 + (float)w2[7] * D3;
            float n3 = (float)pbq[r][3]
                + (float)w3[0] * u2 + (float)w3[1] * u3 + (float)w3[2] * ur
                + (float)w3[3] * C2 + (float)w3[4] * cr
                + (float)w3[5] * D2 + (float)w3[6] * D3 + (float)w3[7] * dr;
            u0 = C0; u1 = C1; u2 = C2; u3 = C3; ul = cl; ur = cr;
            cl = dl; cr = dr;
            s[r][0] = n0; s[r][1] = n1; s[r][2] = n2; s[r][3] = n3;
        }
    }

    // Store the 48x48 core (strips/quads 2..13 inclusive).
    bool core = (qx >= 2) & (qx < 14) & (sy >= 2) & (sy < 14);
    if (core && xok) {
#pragma unroll
        for (int r = 0; r < 4; ++r) {
            int gy = gyb + r;                       // in [0,480) by construction
            size_t gb = plane + (size_t)gy * W + gx0;
            if (LAST) {
                *(float4*)(dst32 + gb) = make_float4(s[r][0], s[r][1], s[r][2], s[r][3]);
            } else {
                half4 hv;
                hv[0] = (_Float16)s[r][0]; hv[1] = (_Float16)s[r][1];
                hv[2] = (_Float16)s[r][2]; hv[3] = (_Float16)s[r][3];
                *(half4*)(dst + gb) = hv;
            }
        }
    }
}

// ---------------------------------------------------------------------------
extern "C" void kernel_launch(void* const* d_in, const int* in_sizes, int n_in,
                              void* d_out, int out_size, void* d_ws, size_t ws_size,
                              hipStream_t stream) {
    const float* guidance = (const float*)d_in[0];
    const float* raw      = (const float*)d_in[1];
    float* out = (float*)d_out;

    const int B = 8, H = 480, W = 640;
    const size_t npix = (size_t)B * H * W;

    // Workspace: wgt half8 (npix*16B) | bias fp16 | p0 fp16 | p1 fp16
    half8*    wgt  = (half8*)d_ws;
    _Float16* bias = (_Float16*)((char*)d_ws + npix * sizeof(half8));
    _Float16* p0   = bias + npix;
    _Float16* p1   = p0 + npix;

    {
        int blocks = (int)((npix + 255) / 256);
        precompute_kernel<<<blocks, 256, 0, stream>>>(guidance, raw, wgt, bias,
                                                      p0, B, H, W);
    }

    // 3 launches x FUSE=8 = 24 iterations. p0 -> p1 -> p0 -> out(f32).
    prop_fused_kernel<false><<<NBLK, 256, 0, stream>>>(p0, wgt, bias, p1, nullptr);
    prop_fused_kernel<false><<<NBLK, 256, 0, stream>>>(p1, wgt, bias, p0, nullptr);
    prop_fused_kernel<true ><<<NBLK, 256, 0, stream>>>(p0, wgt, bias, nullptr, out);
}

// Round 9
// 116.222 us; speedup vs baseline: 5.9502x; 5.9502x over previous
//
#include <hip/hip_runtime.h>
#include <hip/hip_fp16.h>

// Affinity propagation: 24 Jacobi iterations of an 8-neighbor weighted stencil.
// OFFSETS (dy,dx): (-1,-1),(-1,0),(-1,1),(0,-1),(0,1),(1,-1),(1,0),(1,1)
// R9 = R7 (register-resident state, DPP horizontal exchange, LDS vertical
// exchange, FUSE=8 x 3 launches, natural VGPR allocation) + flush-edge
// tiling: at image boundaries zero-pad makes outside-tile=0 EXACT, so edge
// tiles keep no recompute ring on boundary sides -> 13x10 tiles (was 14x10),
// all tiles fully in-image horizontally (x-guards removed). NBLK 1120->1040.
// NOTE: __launch_bounds__(256,4) in R8 capped VGPR at 64 -> scratch spills,
// FETCH 463MB/dispatch, 6.6x regression. Never force occupancy here.

#define EPSV 1e-6f
#define FUSE   8
#define TXN    13                 // 56 + 11*48 + 56 = 640
#define TYN    10                 // 56 + 8*48 + (40 used of 56) = 480
#define NBLK   (8 * TXN * TYN)    // 1040

typedef __attribute__((ext_vector_type(8))) _Float16 half8;
typedef __attribute__((ext_vector_type(4))) _Float16 half4;

__device__ __forceinline__ float dpp_from_left(float v) {
    // lane i gets lane i-1's v (within 16-lane DPP row); qx==0 -> 0.
    int r = __builtin_amdgcn_update_dpp(0, __float_as_int(v), 0x111, 0xF, 0xF, true);
    return __int_as_float(r);
}
__device__ __forceinline__ float dpp_from_right(float v) {
    // lane i gets lane i+1's v; qx==15 -> 0.
    int r = __builtin_amdgcn_update_dpp(0, __float_as_int(v), 0x101, 0xF, 0xF, true);
    return __int_as_float(r);
}

// ---------------------------------------------------------------------------
// Kernel 1: normalize guidance -> fp16 weights (AoS), fp16 bias, fp16 state.
// ---------------------------------------------------------------------------
__global__ __launch_bounds__(256) void precompute_kernel(
    const float* __restrict__ guidance, const float* __restrict__ raw,
    half8* __restrict__ wgt, _Float16* __restrict__ bias,
    _Float16* __restrict__ state, int B, int H, int W)
{
    int idx = blockIdx.x * blockDim.x + threadIdx.x;
    int total = B * H * W;
    if (idx >= total) return;
    int x = idx % W;
    int y = (idx / W) % H;
    int b = idx / (W * H);

    const int dy[8] = {-1,-1,-1, 0, 0, 1, 1, 1};
    const int dx[8] = {-1, 0, 1,-1, 1,-1, 0, 1};

    float g[8];
    float s = 0.f;
#pragma unroll
    for (int c = 0; c < 8; ++c) {
        int yy = y + dy[c], xx = x + dx[c];
        float v = 0.f;
        if (yy >= 0 && yy < H && xx >= 0 && xx < W)
            v = guidance[(((size_t)b * 8 + c) * H + yy) * W + xx];
        g[c] = v;
        s += fabsf(v);
    }
    float inv = 1.f / fmaxf(s, EPSV);
    float wsum = 0.f;
#pragma unroll
    for (int c = 0; c < 8; ++c) { g[c] *= inv; wsum += g[c]; }

    half8 hw;
#pragma unroll
    for (int c = 0; c < 8; ++c) hw[c] = (_Float16)g[c];
    wgt[idx] = hw;

    float r = raw[idx];
    bias[idx]  = (_Float16)((1.f - wsum) * r);
    state[idx] = (_Float16)r;
}

// ---------------------------------------------------------------------------
// Kernel 2: FUSE Jacobi iterations with state in registers.
// Tile = 64x64 px at origin (48*tx, 48*ty); outside-tile treated as 0 each
// iteration. After k iters, px at distance >= k from a tile edge are exact;
// px near an IMAGE boundary edge are exact at any k (zero-pad makes the
// implicit zeros correct). Core = [cxlo,cxhi)x[cylo,cyhi): 8-px ring only on
// interior-seam sides. Cores tile the image disjointly; last launch writes
// every output px exactly once. Out-of-image px (ty==TYN-1 rows past H) have
// w=0,b=0,s=0 -> stay 0 and are never stored.
// ---------------------------------------------------------------------------
template<bool LAST>
__global__ __launch_bounds__(256) void prop_fused_kernel(
    const _Float16* __restrict__ src, const half8* __restrict__ wgt,
    const _Float16* __restrict__ bias, _Float16* __restrict__ dst,
    float* __restrict__ dst32)
{
    const int H = 480, W = 640;
    // bufTop[p][s][x]: strip s's row0 (read as "below-row" by strip s-1 at
    // index s; slot 16 stays 0). bufBot[p][s+1][x]: strip s's row3 (read as
    // "above-row" by strip s+1 at index s+1; slot 0 stays 0).
    __shared__ __align__(16) float bufTop[2][17][64];
    __shared__ __align__(16) float bufBot[2][17][64];

    int tid = threadIdx.x;
    int qx = tid & 15;          // x-quad within tile (DPP row position)
    int sy = tid >> 4;          // 4-row strip within tile

    int t = blockIdx.x;
    int tx = t % TXN;
    int tmp = t / TXN;
    int ty = tmp % TYN;
    int b  = tmp / TYN;
    int x0 = 48 * tx;           // tile fully in-image horizontally
    int y0 = 48 * ty;           // rows >= H only for ty == TYN-1
    size_t plane = (size_t)b * H * W;

    int gx0 = x0 + qx * 4;      // always in [0, 636]
    int gyb = y0 + sy * 4;

    if (tid < 64) {
        bufBot[0][0][tid]  = 0.f; bufBot[1][0][tid]  = 0.f;
        bufTop[0][16][tid] = 0.f; bufTop[1][16][tid] = 0.f;
    }

    // Per-px weights (half8 = 4 VGPR), bias packed fp16, state f32.
    half8 pw[4][4];
    half4 pbq[4];
    float s[4][4];
#pragma unroll
    for (int r = 0; r < 4; ++r) {
        int gy = gyb + r;
        if (gy < H) {
            size_t gb = plane + (size_t)gy * W + gx0;
            const half8* wp = wgt + gb;
            pw[r][0] = wp[0]; pw[r][1] = wp[1]; pw[r][2] = wp[2]; pw[r][3] = wp[3];
            pbq[r] = *(const half4*)(bias + gb);
            half4 sq = *(const half4*)(src + gb);
#pragma unroll
            for (int c = 0; c < 4; ++c) s[r][c] = (float)sq[c];
        } else {
            half8 hz;
#pragma unroll
            for (int c = 0; c < 8; ++c) hz[c] = (_Float16)0.f;
            half4 z4;
#pragma unroll
            for (int c = 0; c < 4; ++c) z4[c] = (_Float16)0.f;
            pbq[r] = z4;
#pragma unroll
            for (int c = 0; c < 4; ++c) { pw[r][c] = hz; s[r][c] = 0.f; }
        }
    }

#pragma unroll 2
    for (int it = 0; it < FUSE; ++it) {
        const int p = it & 1;
        // Exchange strip-boundary rows (old values).
        *(float4*)&bufTop[p][sy][qx * 4]     = make_float4(s[0][0], s[0][1], s[0][2], s[0][3]);
        *(float4*)&bufBot[p][sy + 1][qx * 4] = make_float4(s[3][0], s[3][1], s[3][2], s[3][3]);
        __syncthreads();
        float4 Av = *(const float4*)&bufBot[p][sy][qx * 4];      // row above strip
        float4 Bv = *(const float4*)&bufTop[p][sy + 1][qx * 4];  // row below strip

        // Rolling in-place update (wave-uniform, so DPP of carry regs is safe).
        float u0 = Av.x, u1 = Av.y, u2 = Av.z, u3 = Av.w;
        float ul = dpp_from_left(u3);
        float ur = dpp_from_right(u0);
        float cl = dpp_from_left(s[0][3]);
        float cr = dpp_from_right(s[0][0]);
#pragma unroll
        for (int r = 0; r < 4; ++r) {
            float D0, D1, D2, D3;
            if (r < 3) { D0 = s[r+1][0]; D1 = s[r+1][1]; D2 = s[r+1][2]; D3 = s[r+1][3]; }
            else       { D0 = Bv.x;      D1 = Bv.y;      D2 = Bv.z;      D3 = Bv.w; }
            float dl = dpp_from_left(D3);
            float dr = dpp_from_right(D0);
            float C0 = s[r][0], C1 = s[r][1], C2 = s[r][2], C3 = s[r][3];
            half8 w0 = pw[r][0], w1 = pw[r][1], w2 = pw[r][2], w3 = pw[r][3];
            float n0 = (float)pbq[r][0]
                + (float)w0[0] * ul + (float)w0[1] * u0 + (float)w0[2] * u1
                + (float)w0[3] * cl + (float)w0[4] * C1
                + (float)w0[5] * dl + (float)w0[6] * D0 + (float)w0[7] * D1;
            float n1 = (float)pbq[r][1]
                + (float)w1[0] * u0 + (float)w1[1] * u1 + (float)w1[2] * u2
                + (float)w1[3] * C0 + (float)w1[4] * C2
                + (float)w1[5] * D0 + (float)w1[6] * D1 + (float)w1[7] * D2;
            float n2 = (float)pbq[r][2]
                + (float)w2[0] * u1 + (float)w2[1] * u2 + (float)w2[2] * u3
                + (float)w2[3] * C1 + (float)w2[4] * C3
                + (float)w2[5] * D1 + (float)w2[6] * D2 + (float)w2[7] * D3;
            float n3 = (float)pbq[r][3]
                + (float)w3[0] * u2 + (float)w3[1] * u3 + (float)w3[2] * ur
                + (float)w3[3] * C2 + (float)w3[4] * cr
                + (float)w3[5] * D2 + (float)w3[6] * D3 + (float)w3[7] * dr;
            u0 = C0; u1 = C1; u2 = C2; u3 = C3; ul = cl; ur = cr;
            cl = dl; cr = dr;
            s[r][0] = n0; s[r][1] = n1; s[r][2] = n2; s[r][3] = n3;
        }
    }

    // Store the core (8-px ring only on interior-seam sides; quads and core
    // bounds are 4-aligned so each quad is fully in or out in x).
    int cxlo = (tx == 0) ? 0 : 8;
    int cxhi = (tx == TXN - 1) ? 64 : 56;
    int cylo = (ty == 0) ? 0 : 8;
    int cyhi = (ty == TYN - 1) ? 64 : 56;
    bool corex = (qx * 4 >= cxlo) & (qx * 4 < cxhi);
    if (corex) {
#pragma unroll
        for (int r = 0; r < 4; ++r) {
            int ryy = sy * 4 + r;
            int gy = gyb + r;
            if (ryy >= cylo && ryy < cyhi && gy < H) {
                size_t gb = plane + (size_t)gy * W + gx0;
                if (LAST) {
                    *(float4*)(dst32 + gb) = make_float4(s[r][0], s[r][1], s[r][2], s[r][3]);
                } else {
                    half4 hv;
                    hv[0] = (_Float16)s[r][0]; hv[1] = (_Float16)s[r][1];
                    hv[2] = (_Float16)s[r][2]; hv[3] = (_Float16)s[r][3];
                    *(half4*)(dst + gb) = hv;
                }
            }
        }
    }
}

// ---------------------------------------------------------------------------
extern "C" void kernel_launch(void* const* d_in, const int* in_sizes, int n_in,
                              void* d_out, int out_size, void* d_ws, size_t ws_size,
                              hipStream_t stream) {
    const float* guidance = (const float*)d_in[0];
    const float* raw      = (const float*)d_in[1];
    float* out = (float*)d_out;

    const int B = 8, H = 480, W = 640;
    const size_t npix = (size_t)B * H * W;

    // Workspace: wgt half8 (npix*16B) | bias fp16 | p0 fp16 | p1 fp16
    half8*    wgt  = (half8*)d_ws;
    _Float16* bias = (_Float16*)((char*)d_ws + npix * sizeof(half8));
    _Float16* p0   = bias + npix;
    _Float16* p1   = p0 + npix;

    {
        int blocks = (int)((npix + 255) / 256);
        precompute_kernel<<<blocks, 256, 0, stream>>>(guidance, raw, wgt, bias,
                                                      p0, B, H, W);
    }

    // 3 launches x FUSE=8 = 24 iterations. p0 -> p1 -> p0 -> out(f32).
    prop_fused_kernel<false><<<NBLK, 256, 0, stream>>>(p0, wgt, bias, p1, nullptr);
    prop_fused_kernel<false><<<NBLK, 256, 0, stream>>>(p1, wgt, bias, p0, nullptr);
    prop_fused_kernel<true ><<<NBLK, 256, 0, stream>>>(p0, wgt, bias, nullptr, out);
}

// Round 10
// 115.411 us; speedup vs baseline: 5.9920x; 1.0070x over previous
//
#include <hip/hip_runtime.h>
#include <hip/hip_fp16.h>

// Affinity propagation: 24 Jacobi iterations of an 8-neighbor weighted stencil.
// OFFSETS (dy,dx): (-1,-1),(-1,0),(-1,1),(0,-1),(0,1),(1,-1),(1,0),(1,1)
// R10 = R7 verbatim (register-resident state, DPP horizontal exchange, LDS
// vertical exchange, FUSE=8 x 3 launches, float bias registers, natural VGPR
// allocation) + flush-edge tiling ONLY: at image boundaries zero-pad makes
// outside-tile=0 exact, so edge tiles need no recompute ring on boundary
// sides -> 13x10 tiles, all fully in-image in x (x-guards gone), NBLK 1040.
// De-confounds R9 (which also packed bias to half4 — suspected regression).
// LESSONS: __launch_bounds__(256,4) caps VGPR at 64 -> scratch spill (R8,
// 6.6x slower). Packed-f16 bias seed in the FMA chain suspected -2.. -12us (R9).

#define EPSV 1e-6f
#define FUSE   8
#define TXN    13                 // 56 + 11*48 + 56 = 640
#define TYN    10                 // 56 + 8*48 + 40(of 56) = 480
#define NBLK   (8 * TXN * TYN)    // 1040

typedef __attribute__((ext_vector_type(8))) _Float16 half8;
typedef __attribute__((ext_vector_type(4))) _Float16 half4;

__device__ __forceinline__ float dpp_from_left(float v) {
    // lane i gets lane i-1's v (within 16-lane DPP row); qx==0 -> 0.
    int r = __builtin_amdgcn_update_dpp(0, __float_as_int(v), 0x111, 0xF, 0xF, true);
    return __int_as_float(r);
}
__device__ __forceinline__ float dpp_from_right(float v) {
    // lane i gets lane i+1's v; qx==15 -> 0.
    int r = __builtin_amdgcn_update_dpp(0, __float_as_int(v), 0x101, 0xF, 0xF, true);
    return __int_as_float(r);
}

// ---------------------------------------------------------------------------
// Kernel 1: normalize guidance -> fp16 weights (AoS), fp16 bias, fp16 state.
// ---------------------------------------------------------------------------
__global__ __launch_bounds__(256) void precompute_kernel(
    const float* __restrict__ guidance, const float* __restrict__ raw,
    half8* __restrict__ wgt, _Float16* __restrict__ bias,
    _Float16* __restrict__ state, int B, int H, int W)
{
    int idx = blockIdx.x * blockDim.x + threadIdx.x;
    int total = B * H * W;
    if (idx >= total) return;
    int x = idx % W;
    int y = (idx / W) % H;
    int b = idx / (W * H);

    const int dy[8] = {-1,-1,-1, 0, 0, 1, 1, 1};
    const int dx[8] = {-1, 0, 1,-1, 1,-1, 0, 1};

    float g[8];
    float s = 0.f;
#pragma unroll
    for (int c = 0; c < 8; ++c) {
        int yy = y + dy[c], xx = x + dx[c];
        float v = 0.f;
        if (yy >= 0 && yy < H && xx >= 0 && xx < W)
            v = guidance[(((size_t)b * 8 + c) * H + yy) * W + xx];
        g[c] = v;
        s += fabsf(v);
    }
    float inv = 1.f / fmaxf(s, EPSV);
    float wsum = 0.f;
#pragma unroll
    for (int c = 0; c < 8; ++c) { g[c] *= inv; wsum += g[c]; }

    half8 hw;
#pragma unroll
    for (int c = 0; c < 8; ++c) hw[c] = (_Float16)g[c];
    wgt[idx] = hw;

    float r = raw[idx];
    bias[idx]  = (_Float16)((1.f - wsum) * r);
    state[idx] = (_Float16)r;
}

// ---------------------------------------------------------------------------
// Kernel 2: FUSE Jacobi iterations with state in registers.
// Tile = 64x64 px at origin (48*tx, 48*ty); outside-tile treated as 0 each
// iteration. After k iters, px at distance >= k from a tile edge are exact;
// px adjacent to an IMAGE boundary are exact at any k (zero-pad makes the
// implicit zeros correct). Core = [cxlo,cxhi)x[cylo,cyhi): 8-px ring only on
// interior-seam sides. Cores tile the image disjointly; every launch writes
// every output px exactly once. Rows past H (ty==TYN-1) have w=0,b=0,s=0 ->
// stay 0 and are never stored.
// ---------------------------------------------------------------------------
template<bool LAST>
__global__ __launch_bounds__(256) void prop_fused_kernel(
    const _Float16* __restrict__ src, const half8* __restrict__ wgt,
    const _Float16* __restrict__ bias, _Float16* __restrict__ dst,
    float* __restrict__ dst32)
{
    const int H = 480, W = 640;
    // bufTop[p][s][x]: strip s's row0 (read as "below-row" by strip s-1 at
    // index s; slot 16 stays 0). bufBot[p][s+1][x]: strip s's row3 (read as
    // "above-row" by strip s+1 at index s+1; slot 0 stays 0).
    __shared__ __align__(16) float bufTop[2][17][64];
    __shared__ __align__(16) float bufBot[2][17][64];

    int tid = threadIdx.x;
    int qx = tid & 15;          // x-quad within tile (DPP row position)
    int sy = tid >> 4;          // 4-row strip within tile

    int t = blockIdx.x;
    int tx = t % TXN;
    int tmp = t / TXN;
    int ty = tmp % TYN;
    int b  = tmp / TYN;
    int x0 = 48 * tx;           // tile fully in-image horizontally
    int y0 = 48 * ty;           // rows >= H only for ty == TYN-1
    size_t plane = (size_t)b * H * W;

    int gx0 = x0 + qx * 4;      // always in [0, 636]
    int gyb = y0 + sy * 4;

    if (tid < 64) {
        bufBot[0][0][tid]  = 0.f; bufBot[1][0][tid]  = 0.f;
        bufTop[0][16][tid] = 0.f; bufTop[1][16][tid] = 0.f;
    }

    // Per-px weights (half8 = 4 VGPR), bias f32, state f32 — static-indexed.
    half8 pw[4][4];
    float pb[4][4];
    float s[4][4];
#pragma unroll
    for (int r = 0; r < 4; ++r) {
        int gy = gyb + r;
        if (gy < H) {
            size_t gb = plane + (size_t)gy * W + gx0;
            const half8* wp = wgt + gb;
            pw[r][0] = wp[0]; pw[r][1] = wp[1]; pw[r][2] = wp[2]; pw[r][3] = wp[3];
            half4 bq = *(const half4*)(bias + gb);
            half4 sq = *(const half4*)(src + gb);
#pragma unroll
            for (int c = 0; c < 4; ++c) {
                pb[r][c] = (float)bq[c];
                s[r][c]  = (float)sq[c];
            }
        } else {
            half8 hz;
#pragma unroll
            for (int c = 0; c < 8; ++c) hz[c] = (_Float16)0.f;
#pragma unroll
            for (int c = 0; c < 4; ++c) {
                pw[r][c] = hz; pb[r][c] = 0.f; s[r][c] = 0.f;
            }
        }
    }

#pragma unroll 2
    for (int it = 0; it < FUSE; ++it) {
        const int p = it & 1;
        // Exchange strip-boundary rows (old values).
        *(float4*)&bufTop[p][sy][qx * 4]     = make_float4(s[0][0], s[0][1], s[0][2], s[0][3]);
        *(float4*)&bufBot[p][sy + 1][qx * 4] = make_float4(s[3][0], s[3][1], s[3][2], s[3][3]);
        __syncthreads();
        float4 Av = *(const float4*)&bufBot[p][sy][qx * 4];      // row above strip
        float4 Bv = *(const float4*)&bufTop[p][sy + 1][qx * 4];  // row below strip

        // Rolling in-place update (wave-uniform, so DPP of carry regs is safe).
        float u0 = Av.x, u1 = Av.y, u2 = Av.z, u3 = Av.w;
        float ul = dpp_from_left(u3);
        float ur = dpp_from_right(u0);
        float cl = dpp_from_left(s[0][3]);
        float cr = dpp_from_right(s[0][0]);
#pragma unroll
        for (int r = 0; r < 4; ++r) {
            float D0, D1, D2, D3;
            if (r < 3) { D0 = s[r+1][0]; D1 = s[r+1][1]; D2 = s[r+1][2]; D3 = s[r+1][3]; }
            else       { D0 = Bv.x;      D1 = Bv.y;      D2 = Bv.z;      D3 = Bv.w; }
            float dl = dpp_from_left(D3);
            float dr = dpp_from_right(D0);
            float C0 = s[r][0], C1 = s[r][1], C2 = s[r][2], C3 = s[r][3];
            half8 w0 = pw[r][0], w1 = pw[r][1], w2 = pw[r][2], w3 = pw[r][3];
            float n0 = pb[r][0]
                + (float)w0[0] * ul + (float)w0[1] * u0 + (float)w0[2] * u1
                + (float)w0[3] * cl + (float)w0[4] * C1
                + (float)w0[5] * dl + (float)w0[6] * D0 + (float)w0[7] * D1;
            float n1 = pb[r][1]
                + (float)w1[0] * u0 + (float)w1[1] * u1 + (float)w1[2] * u2
                + (float)w1[3] * C0 + (float)w1[4] * C2
                + (float)w1[5] * D0 + (float)w1[6] * D1 + (float)w1[7] * D2;
            float n2 = pb[r][2]
                + (float)w2[0] * u1 + (float)w2[1] * u2 + (float)w2[2] * u3
                + (float)w2[3] * C1 + (float)w2[4] * C3
                + (float)w2[5] * D1 + (float)w2[6] * D2 + (float)w2[7] * D3;
            float n3 = pb[r][3]
                + (float)w3[0] * u2 + (float)w3[1] * u3 + (float)w3[2] * ur
                + (float)w3[3] * C2 + (float)w3[4] * cr
                + (float)w3[5] * D2 + (float)w3[6] * D3 + (float)w3[7] * dr;
            u0 = C0; u1 = C1; u2 = C2; u3 = C3; ul = cl; ur = cr;
            cl = dl; cr = dr;
            s[r][0] = n0; s[r][1] = n1; s[r][2] = n2; s[r][3] = n3;
        }
    }

    // Store the core (8-px ring only on interior-seam sides; quads and core
    // bounds are 4-aligned so each quad is fully in or out in x).
    int cxlo = (tx == 0) ? 0 : 8;
    int cxhi = (tx == TXN - 1) ? 64 : 56;
    int cylo = (ty == 0) ? 0 : 8;
    int cyhi = (ty == TYN - 1) ? 64 : 56;
    bool corex = (qx * 4 >= cxlo) & (qx * 4 < cxhi);
    if (corex) {
#pragma unroll
        for (int r = 0; r < 4; ++r) {
            int ryy = sy * 4 + r;
            int gy = gyb + r;
            if (ryy >= cylo && ryy < cyhi && gy < H) {
                size_t gb = plane + (size_t)gy * W + gx0;
                if (LAST) {
                    *(float4*)(dst32 + gb) = make_float4(s[r][0], s[r][1], s[r][2], s[r][3]);
                } else {
                    half4 hv;
                    hv[0] = (_Float16)s[r][0]; hv[1] = (_Float16)s[r][1];
                    hv[2] = (_Float16)s[r][2]; hv[3] = (_Float16)s[r][3];
                    *(half4*)(dst + gb) = hv;
                }
            }
        }
    }
}

// ---------------------------------------------------------------------------
extern "C" void kernel_launch(void* const* d_in, const int* in_sizes, int n_in,
                              void* d_out, int out_size, void* d_ws, size_t ws_size,
                              hipStream_t stream) {
    const float* guidance = (const float*)d_in[0];
    const float* raw      = (const float*)d_in[1];
    float* out = (float*)d_out;

    const int B = 8, H = 480, W = 640;
    const size_t npix = (size_t)B * H * W;

    // Workspace: wgt half8 (npix*16B) | bias fp16 | p0 fp16 | p1 fp16
    half8*    wgt  = (half8*)d_ws;
    _Float16* bias = (_Float16*)((char*)d_ws + npix * sizeof(half8));
    _Float16* p0   = bias + npix;
    _Float16* p1   = p0 + npix;

    {
        int blocks = (int)((npix + 255) / 256);
        precompute_kernel<<<blocks, 256, 0, stream>>>(guidance, raw, wgt, bias,
                                                      p0, B, H, W);
    }

    // 3 launches x FUSE=8 = 24 iterations. p0 -> p1 -> p0 -> out(f32).
    prop_fused_kernel<false><<<NBLK, 256, 0, stream>>>(p0, wgt, bias, p1, nullptr);
    prop_fused_kernel<false><<<NBLK, 256, 0, stream>>>(p1, wgt, bias, p0, nullptr);
    prop_fused_kernel<true ><<<NBLK, 256, 0, stream>>>(p0, wgt, bias, nullptr, out);
}

// Round 11
// 104.428 us; speedup vs baseline: 6.6222x; 1.1052x over previous
//
#include <hip/hip_runtime.h>
#include <hip/hip_fp16.h>

// Affinity propagation: 24 Jacobi iterations of an 8-neighbor weighted stencil.
// OFFSETS (dy,dx): (-1,-1),(-1,0),(-1,1),(0,-1),(0,1),(1,-1),(1,0),(1,1)
// R11 = R7 VERBATIM re-run (A/B anchor). R9/R10 (flush tiling, runtime core
// bounds) were ~115.5us vs R7's 104.5us; hypothesis: runtime store bounds
// pushed VGPR over the 128 cliff (4->2 blocks/CU). This round re-measures R7
// to separate "flush tiling regressed (VGPR cliff)" from "R7 was a fast run".
// LESSONS: __launch_bounds__(256,4) clamps VGPR to 64 -> scratch spill (R8).
// Keep store predicates static (lane-pattern), not runtime-per-tile.

#define EPSV 1e-6f
#define FUSE   8
#define CORE   48                 // output core per 64x64 tile
#define TXN    14                 // ceil(640/48)
#define TYN    10                 // 480/48
#define NBLK   (8 * TXN * TYN)    // 1120

typedef __attribute__((ext_vector_type(8))) _Float16 half8;
typedef __attribute__((ext_vector_type(4))) _Float16 half4;

__device__ __forceinline__ float dpp_from_left(float v) {
    // lane i gets lane i-1's v (within 16-lane DPP row); qx==0 -> 0.
    int r = __builtin_amdgcn_update_dpp(0, __float_as_int(v), 0x111, 0xF, 0xF, true);
    return __int_as_float(r);
}
__device__ __forceinline__ float dpp_from_right(float v) {
    // lane i gets lane i+1's v; qx==15 -> 0.
    int r = __builtin_amdgcn_update_dpp(0, __float_as_int(v), 0x101, 0xF, 0xF, true);
    return __int_as_float(r);
}

// ---------------------------------------------------------------------------
// Kernel 1: normalize guidance -> fp16 weights (AoS), fp16 bias, fp16 state.
// ---------------------------------------------------------------------------
__global__ __launch_bounds__(256) void precompute_kernel(
    const float* __restrict__ guidance, const float* __restrict__ raw,
    half8* __restrict__ wgt, _Float16* __restrict__ bias,
    _Float16* __restrict__ state, int B, int H, int W)
{
    int idx = blockIdx.x * blockDim.x + threadIdx.x;
    int total = B * H * W;
    if (idx >= total) return;
    int x = idx % W;
    int y = (idx / W) % H;
    int b = idx / (W * H);

    const int dy[8] = {-1,-1,-1, 0, 0, 1, 1, 1};
    const int dx[8] = {-1, 0, 1,-1, 1,-1, 0, 1};

    float g[8];
    float s = 0.f;
#pragma unroll
    for (int c = 0; c < 8; ++c) {
        int yy = y + dy[c], xx = x + dx[c];
        float v = 0.f;
        if (yy >= 0 && yy < H && xx >= 0 && xx < W)
            v = guidance[(((size_t)b * 8 + c) * H + yy) * W + xx];
        g[c] = v;
        s += fabsf(v);
    }
    float inv = 1.f / fmaxf(s, EPSV);
    float wsum = 0.f;
#pragma unroll
    for (int c = 0; c < 8; ++c) { g[c] *= inv; wsum += g[c]; }

    half8 hw;
#pragma unroll
    for (int c = 0; c < 8; ++c) hw[c] = (_Float16)g[c];
    wgt[idx] = hw;

    float r = raw[idx];
    bias[idx]  = (_Float16)((1.f - wsum) * r);
    state[idx] = (_Float16)r;
}

// ---------------------------------------------------------------------------
// Kernel 2: FUSE Jacobi iterations with state in registers.
// Tile = 64x64 owned px; outside-tile treated as 0 each iteration (recompute
// ring): after k iters px at distance >= k from tile edge are exact, so the
// 48x48 core (distance 8) is exact at k=FUSE=8. Out-of-image px have
// w=0,b=0,s=0 -> stay 0, matching zero-pad semantics. Cores tile the image
// disjointly, so the last launch writes every output px exactly once.
// ---------------------------------------------------------------------------
template<bool LAST>
__global__ __launch_bounds__(256) void prop_fused_kernel(
    const _Float16* __restrict__ src, const half8* __restrict__ wgt,
    const _Float16* __restrict__ bias, _Float16* __restrict__ dst,
    float* __restrict__ dst32)
{
    const int H = 480, W = 640;
    // bufTop[p][s][x]: strip s's row0 (read as "below-row" by strip s-1 at
    // index s; slot 16 stays 0). bufBot[p][s+1][x]: strip s's row3 (read as
    // "above-row" by strip s+1 at index s+1; slot 0 stays 0).
    __shared__ __align__(16) float bufTop[2][17][64];
    __shared__ __align__(16) float bufBot[2][17][64];

    int tid = threadIdx.x;
    int qx = tid & 15;          // x-quad within tile (DPP row position)
    int sy = tid >> 4;          // 4-row strip within tile

    int t = blockIdx.x;
    int tx = t % TXN;
    int tmp = t / TXN;
    int ty = tmp % TYN;
    int b  = tmp / TYN;
    int x0 = tx * CORE - FUSE;
    int y0 = ty * CORE - FUSE;
    size_t plane = (size_t)b * H * W;

    int gx0 = x0 + qx * 4;                       // quad is fully in or out
    bool xok = (gx0 >= 0) & (gx0 + 3 < W);
    int gyb = y0 + sy * 4;

    if (tid < 64) {
        bufBot[0][0][tid]  = 0.f; bufBot[1][0][tid]  = 0.f;
        bufTop[0][16][tid] = 0.f; bufTop[1][16][tid] = 0.f;
    }

    // Per-px weights (half8 = 4 VGPR), bias f32, state f32 — all static-indexed.
    half8 pw[4][4];
    float pb[4][4];
    float s[4][4];
#pragma unroll
    for (int r = 0; r < 4; ++r) {
        int gy = gyb + r;
        bool ok = xok && gy >= 0 && gy < H;
        if (ok) {
            size_t gb = plane + (size_t)gy * W + gx0;
            const half8* wp = wgt + gb;
            pw[r][0] = wp[0]; pw[r][1] = wp[1]; pw[r][2] = wp[2]; pw[r][3] = wp[3];
            half4 bq = *(const half4*)(bias + gb);
            half4 sq = *(const half4*)(src + gb);
#pragma unroll
            for (int c = 0; c < 4; ++c) {
                pb[r][c] = (float)bq[c];
                s[r][c]  = (float)sq[c];
            }
        } else {
            half8 hz;
#pragma unroll
            for (int c = 0; c < 8; ++c) hz[c] = (_Float16)0.f;
#pragma unroll
            for (int c = 0; c < 4; ++c) {
                pw[r][c] = hz; pb[r][c] = 0.f; s[r][c] = 0.f;
            }
        }
    }

#pragma unroll 2
    for (int it = 0; it < FUSE; ++it) {
        const int p = it & 1;
        // Exchange strip-boundary rows (old values).
        *(float4*)&bufTop[p][sy][qx * 4]     = make_float4(s[0][0], s[0][1], s[0][2], s[0][3]);
        *(float4*)&bufBot[p][sy + 1][qx * 4] = make_float4(s[3][0], s[3][1], s[3][2], s[3][3]);
        __syncthreads();
        float4 Av = *(const float4*)&bufBot[p][sy][qx * 4];      // row above strip
        float4 Bv = *(const float4*)&bufTop[p][sy + 1][qx * 4];  // row below strip

        // Rolling in-place update (wave-uniform, so DPP of carry regs is safe).
        float u0 = Av.x, u1 = Av.y, u2 = Av.z, u3 = Av.w;
        float ul = dpp_from_left(u3);
        float ur = dpp_from_right(u0);
        float cl = dpp_from_left(s[0][3]);
        float cr = dpp_from_right(s[0][0]);
#pragma unroll
        for (int r = 0; r < 4; ++r) {
            float D0, D1, D2, D3;
            if (r < 3) { D0 = s[r+1][0]; D1 = s[r+1][1]; D2 = s[r+1][2]; D3 = s[r+1][3]; }
            else       { D0 = Bv.x;      D1 = Bv.y;      D2 = Bv.z;      D3 = Bv.w; }
            float dl = dpp_from_left(D3);
            float dr = dpp_from_right(D0);
            float C0 = s[r][0], C1 = s[r][1], C2 = s[r][2], C3 = s[r][3];
            half8 w0 = pw[r][0], w1 = pw[r][1], w2 = pw[r][2], w3 = pw[r][3];
            float n0 = pb[r][0]
                + (float)w0[0] * ul + (float)w0[1] * u0 + (float)w0[2] * u1
                + (float)w0[3] * cl + (float)w0[4] * C1
                + (float)w0[5] * dl + (float)w0[6] * D0 + (float)w0[7] * D1;
            float n1 = pb[r][1]
                + (float)w1[0] * u0 + (float)w1[1] * u1 + (float)w1[2] * u2
                + (float)w1[3] * C0 + (float)w1[4] * C2
                + (float)w1[5] * D0 + (float)w1[6] * D1 + (float)w1[7] * D2;
            float n2 = pb[r][2]
                + (float)w2[0] * u1 + (float)w2[1] * u2 + (float)w2[2] * u3
                + (float)w2[3] * C1 + (float)w2[4] * C3
                + (float)w2[5] * D1 + (float)w2[6] * D2 + (float)w2[7] * D3;
            float n3 = pb[r][3]
                + (float)w3[0] * u2 + (float)w3[1] * u3 + (float)w3[2] * ur
                + (float)w3[3] * C2 + (float)w3[4] * cr
                + (float)w3[5] * D2 + (float)w3[6] * D3 + (float)w3[7] * dr;
            u0 = C0; u1 = C1; u2 = C2; u3 = C3; ul = cl; ur = cr;
            cl = dl; cr = dr;
            s[r][0] = n0; s[r][1] = n1; s[r][2] = n2; s[r][3] = n3;
        }
    }

    // Store the 48x48 core (strips/quads 2..13 inclusive).
    bool core = (qx >= 2) & (qx < 14) & (sy >= 2) & (sy < 14);
    if (core && xok) {
#pragma unroll
        for (int r = 0; r < 4; ++r) {
            int gy = gyb + r;                       // in [0,480) by construction
            size_t gb = plane + (size_t)gy * W + gx0;
            if (LAST) {
                *(float4*)(dst32 + gb) = make_float4(s[r][0], s[r][1], s[r][2], s[r][3]);
            } else {
                half4 hv;
                hv[0] = (_Float16)s[r][0]; hv[1] = (_Float16)s[r][1];
                hv[2] = (_Float16)s[r][2]; hv[3] = (_Float16)s[r][3];
                *(half4*)(dst + gb) = hv;
            }
        }
    }
}

// ---------------------------------------------------------------------------
extern "C" void kernel_launch(void* const* d_in, const int* in_sizes, int n_in,
                              void* d_out, int out_size, void* d_ws, size_t ws_size,
                              hipStream_t stream) {
    const float* guidance = (const float*)d_in[0];
    const float* raw      = (const float*)d_in[1];
    float* out = (float*)d_out;

    const int B = 8, H = 480, W = 640;
    const size_t npix = (size_t)B * H * W;

    // Workspace: wgt half8 (npix*16B) | bias fp16 | p0 fp16 | p1 fp16
    half8*    wgt  = (half8*)d_ws;
    _Float16* bias = (_Float16*)((char*)d_ws + npix * sizeof(half8));
    _Float16* p0   = bias + npix;
    _Float16* p1   = p0 + npix;

    {
        int blocks = (int)((npix + 255) / 256);
        precompute_kernel<<<blocks, 256, 0, stream>>>(guidance, raw, wgt, bias,
                                                      p0, B, H, W);
    }

    // 3 launches x FUSE=8 = 24 iterations. p0 -> p1 -> p0 -> out(f32).
    prop_fused_kernel<false><<<NBLK, 256, 0, stream>>>(p0, wgt, bias, p1, nullptr);
    prop_fused_kernel<false><<<NBLK, 256, 0, stream>>>(p1, wgt, bias, p0, nullptr);
    prop_fused_kernel<true ><<<NBLK, 256, 0, stream>>>(p0, wgt, bias, nullptr, out);
}

// Round 12
// 96.556 us; speedup vs baseline: 7.1621x; 1.0815x over previous
//
#include <hip/hip_runtime.h>
#include <hip/hip_fp16.h>

// Affinity propagation: 24 Jacobi iterations of an 8-neighbor weighted stencil.
// OFFSETS (dy,dx): (-1,-1),(-1,0),(-1,1),(0,-1),(0,1),(1,-1),(1,0),(1,1)
// R12 = R7/R11 structure (register-resident weights+state, DPP horizontal
// exchange, LDS vertical exchange, static store predicate) with FUSE=12 and
// core 40x40: 640=16*40, 480=12*40 -> cores EXACTLY flush, ring 12 is
// 4-aligned (quads/strips 3..12), stores unconditionally in-image.
// 2 prop launches instead of 3 -> one fewer grid-wide weight-load burst.
// LESSONS: __launch_bounds__(256,4) clamps VGPR->64 = spill disaster (R8).
// Runtime per-tile store bounds regressed ~11us (R9/R10) — keep static.

#define EPSV 1e-6f
#define FUSE   12
#define CORE   40                 // output core per 64x64 tile
#define TXN    16                 // 640 / 40
#define TYN    12                 // 480 / 40
#define NBLK   (8 * TXN * TYN)    // 1536

typedef __attribute__((ext_vector_type(8))) _Float16 half8;
typedef __attribute__((ext_vector_type(4))) _Float16 half4;

__device__ __forceinline__ float dpp_from_left(float v) {
    // lane i gets lane i-1's v (within 16-lane DPP row); qx==0 -> 0.
    int r = __builtin_amdgcn_update_dpp(0, __float_as_int(v), 0x111, 0xF, 0xF, true);
    return __int_as_float(r);
}
__device__ __forceinline__ float dpp_from_right(float v) {
    // lane i gets lane i+1's v; qx==15 -> 0.
    int r = __builtin_amdgcn_update_dpp(0, __float_as_int(v), 0x101, 0xF, 0xF, true);
    return __int_as_float(r);
}

// ---------------------------------------------------------------------------
// Kernel 1: normalize guidance -> fp16 weights (AoS), fp16 bias, fp16 state.
// ---------------------------------------------------------------------------
__global__ __launch_bounds__(256) void precompute_kernel(
    const float* __restrict__ guidance, const float* __restrict__ raw,
    half8* __restrict__ wgt, _Float16* __restrict__ bias,
    _Float16* __restrict__ state, int B, int H, int W)
{
    int idx = blockIdx.x * blockDim.x + threadIdx.x;
    int total = B * H * W;
    if (idx >= total) return;
    int x = idx % W;
    int y = (idx / W) % H;
    int b = idx / (W * H);

    const int dy[8] = {-1,-1,-1, 0, 0, 1, 1, 1};
    const int dx[8] = {-1, 0, 1,-1, 1,-1, 0, 1};

    float g[8];
    float s = 0.f;
#pragma unroll
    for (int c = 0; c < 8; ++c) {
        int yy = y + dy[c], xx = x + dx[c];
        float v = 0.f;
        if (yy >= 0 && yy < H && xx >= 0 && xx < W)
            v = guidance[(((size_t)b * 8 + c) * H + yy) * W + xx];
        g[c] = v;
        s += fabsf(v);
    }
    float inv = 1.f / fmaxf(s, EPSV);
    float wsum = 0.f;
#pragma unroll
    for (int c = 0; c < 8; ++c) { g[c] *= inv; wsum += g[c]; }

    half8 hw;
#pragma unroll
    for (int c = 0; c < 8; ++c) hw[c] = (_Float16)g[c];
    wgt[idx] = hw;

    float r = raw[idx];
    bias[idx]  = (_Float16)((1.f - wsum) * r);
    state[idx] = (_Float16)r;
}

// ---------------------------------------------------------------------------
// Kernel 2: FUSE Jacobi iterations with state in registers.
// Tile = 64x64 px at origin (40*tx-12, 40*ty-12); outside-tile treated as 0
// each iteration (recompute ring): after k iters px at distance >= k from the
// tile edge are exact, so the 40x40 core (distance 12) is exact at k=FUSE=12.
// Out-of-image px have w=0,b=0,s=0 -> stay 0, matching zero-pad semantics.
// Cores tile the image disjointly and exactly (16x12 grid of 40x40).
// ---------------------------------------------------------------------------
template<bool LAST>
__global__ __launch_bounds__(256) void prop_fused_kernel(
    const _Float16* __restrict__ src, const half8* __restrict__ wgt,
    const _Float16* __restrict__ bias, _Float16* __restrict__ dst,
    float* __restrict__ dst32)
{
    const int H = 480, W = 640;
    // bufTop[p][s][x]: strip s's row0 (read as "below-row" by strip s-1 at
    // index s; slot 16 stays 0). bufBot[p][s+1][x]: strip s's row3 (read as
    // "above-row" by strip s+1 at index s+1; slot 0 stays 0).
    __shared__ __align__(16) float bufTop[2][17][64];
    __shared__ __align__(16) float bufBot[2][17][64];

    int tid = threadIdx.x;
    int qx = tid & 15;          // x-quad within tile (DPP row position)
    int sy = tid >> 4;          // 4-row strip within tile

    int t = blockIdx.x;
    int tx = t % TXN;
    int tmp = t / TXN;
    int ty = tmp % TYN;
    int b  = tmp / TYN;
    int x0 = tx * CORE - FUSE;
    int y0 = ty * CORE - FUSE;
    size_t plane = (size_t)b * H * W;

    int gx0 = x0 + qx * 4;                       // quad is fully in or out
    bool xok = (gx0 >= 0) & (gx0 + 3 < W);
    int gyb = y0 + sy * 4;

    if (tid < 64) {
        bufBot[0][0][tid]  = 0.f; bufBot[1][0][tid]  = 0.f;
        bufTop[0][16][tid] = 0.f; bufTop[1][16][tid] = 0.f;
    }

    // Per-px weights (half8 = 4 VGPR), bias f32, state f32 — all static-indexed.
    half8 pw[4][4];
    float pb[4][4];
    float s[4][4];
#pragma unroll
    for (int r = 0; r < 4; ++r) {
        int gy = gyb + r;
        bool ok = xok && gy >= 0 && gy < H;
        if (ok) {
            size_t gb = plane + (size_t)gy * W + gx0;
            const half8* wp = wgt + gb;
            pw[r][0] = wp[0]; pw[r][1] = wp[1]; pw[r][2] = wp[2]; pw[r][3] = wp[3];
            half4 bq = *(const half4*)(bias + gb);
            half4 sq = *(const half4*)(src + gb);
#pragma unroll
            for (int c = 0; c < 4; ++c) {
                pb[r][c] = (float)bq[c];
                s[r][c]  = (float)sq[c];
            }
        } else {
            half8 hz;
#pragma unroll
            for (int c = 0; c < 8; ++c) hz[c] = (_Float16)0.f;
#pragma unroll
            for (int c = 0; c < 4; ++c) {
                pw[r][c] = hz; pb[r][c] = 0.f; s[r][c] = 0.f;
            }
        }
    }

#pragma unroll 2
    for (int it = 0; it < FUSE; ++it) {
        const int p = it & 1;
        // Exchange strip-boundary rows (old values).
        *(float4*)&bufTop[p][sy][qx * 4]     = make_float4(s[0][0], s[0][1], s[0][2], s[0][3]);
        *(float4*)&bufBot[p][sy + 1][qx * 4] = make_float4(s[3][0], s[3][1], s[3][2], s[3][3]);
        __syncthreads();
        float4 Av = *(const float4*)&bufBot[p][sy][qx * 4];      // row above strip
        float4 Bv = *(const float4*)&bufTop[p][sy + 1][qx * 4];  // row below strip

        // Rolling in-place update (wave-uniform, so DPP of carry regs is safe).
        float u0 = Av.x, u1 = Av.y, u2 = Av.z, u3 = Av.w;
        float ul = dpp_from_left(u3);
        float ur = dpp_from_right(u0);
        float cl = dpp_from_left(s[0][3]);
        float cr = dpp_from_right(s[0][0]);
#pragma unroll
        for (int r = 0; r < 4; ++r) {
            float D0, D1, D2, D3;
            if (r < 3) { D0 = s[r+1][0]; D1 = s[r+1][1]; D2 = s[r+1][2]; D3 = s[r+1][3]; }
            else       { D0 = Bv.x;      D1 = Bv.y;      D2 = Bv.z;      D3 = Bv.w; }
            float dl = dpp_from_left(D3);
            float dr = dpp_from_right(D0);
            float C0 = s[r][0], C1 = s[r][1], C2 = s[r][2], C3 = s[r][3];
            half8 w0 = pw[r][0], w1 = pw[r][1], w2 = pw[r][2], w3 = pw[r][3];
            float n0 = pb[r][0]
                + (float)w0[0] * ul + (float)w0[1] * u0 + (float)w0[2] * u1
                + (float)w0[3] * cl + (float)w0[4] * C1
                + (float)w0[5] * dl + (float)w0[6] * D0 + (float)w0[7] * D1;
            float n1 = pb[r][1]
                + (float)w1[0] * u0 + (float)w1[1] * u1 + (float)w1[2] * u2
                + (float)w1[3] * C0 + (float)w1[4] * C2
                + (float)w1[5] * D0 + (float)w1[6] * D1 + (float)w1[7] * D2;
            float n2 = pb[r][2]
                + (float)w2[0] * u1 + (float)w2[1] * u2 + (float)w2[2] * u3
                + (float)w2[3] * C1 + (float)w2[4] * C3
                + (float)w2[5] * D1 + (float)w2[6] * D2 + (float)w2[7] * D3;
            float n3 = pb[r][3]
                + (float)w3[0] * u2 + (float)w3[1] * u3 + (float)w3[2] * ur
                + (float)w3[3] * C2 + (float)w3[4] * cr
                + (float)w3[5] * D2 + (float)w3[6] * D3 + (float)w3[7] * dr;
            u0 = C0; u1 = C1; u2 = C2; u3 = C3; ul = cl; ur = cr;
            cl = dl; cr = dr;
            s[r][0] = n0; s[r][1] = n1; s[r][2] = n2; s[r][3] = n3;
        }
    }

    // Store the 40x40 core: quads/strips 3..12 inclusive. Static lane-pattern
    // predicate; all stored px are unconditionally in-image (cores flush).
    bool core = (qx >= 3) & (qx < 13) & (sy >= 3) & (sy < 13);
    if (core) {
#pragma unroll
        for (int r = 0; r < 4; ++r) {
            int gy = gyb + r;                       // in [0,480) by construction
            size_t gb = plane + (size_t)gy * W + gx0;
            if (LAST) {
                *(float4*)(dst32 + gb) = make_float4(s[r][0], s[r][1], s[r][2], s[r][3]);
            } else {
                half4 hv;
                hv[0] = (_Float16)s[r][0]; hv[1] = (_Float16)s[r][1];
                hv[2] = (_Float16)s[r][2]; hv[3] = (_Float16)s[r][3];
                *(half4*)(dst + gb) = hv;
            }
        }
    }
}

// ---------------------------------------------------------------------------
extern "C" void kernel_launch(void* const* d_in, const int* in_sizes, int n_in,
                              void* d_out, int out_size, void* d_ws, size_t ws_size,
                              hipStream_t stream) {
    const float* guidance = (const float*)d_in[0];
    const float* raw      = (const float*)d_in[1];
    float* out = (float*)d_out;

    const int B = 8, H = 480, W = 640;
    const size_t npix = (size_t)B * H * W;

    // Workspace: wgt half8 (npix*16B) | bias fp16 | p0 fp16 | p1 fp16
    half8*    wgt  = (half8*)d_ws;
    _Float16* bias = (_Float16*)((char*)d_ws + npix * sizeof(half8));
    _Float16* p0   = bias + npix;
    _Float16* p1   = p0 + npix;

    {
        int blocks = (int)((npix + 255) / 256);
        precompute_kernel<<<blocks, 256, 0, stream>>>(guidance, raw, wgt, bias,
                                                      p0, B, H, W);
    }

    // 2 launches x FUSE=12 = 24 iterations. p0 -> p1 -> out(f32).
    prop_fused_kernel<false><<<NBLK, 256, 0, stream>>>(p0, wgt, bias, p1, nullptr);
    prop_fused_kernel<true ><<<NBLK, 256, 0, stream>>>(p1, wgt, bias, nullptr, out);
}